// Round 10
// baseline (400.875 us; speedup 1.0000x reference)
//
#include <hip/hip_runtime.h>
#include <stdint.h>

// ============================================================================
// AttentionBlock: out = concat([x, softmax(QK^T/32) @ V], -1)
//   B=4, S=2048, D=1024, fp32 in/out.
//
// ALGEBRA: S = x Wq Wk^T x^T.  N := Wk Wq^T (split-K over z), T := x N^T,
// S := T x^T.  fp32 via f16 hi/lo split folded into K: A''=[Ah|Al|Ah],
// B''=[Bh|Bh|Bl], K=3072, per-K-region tables + per-z K-base.
//
// GEMM template (BM x BN x TPB threads, BK=64, dbuf LDS, gload_lds + T2
// pre-swizzled source, T1 XCD swizzle). r9's measured-best LAZY-PUBLISH
// schedule (unchanged):
//   P0: dsA0+dsB0; stage B0(t+1)->buf^1; BAR; lgkm0; MFMA A0xB0; vmw<W0>; BAR
//   P1: dsB1;      stage B1(t+1);        BAR; lgkm0; MFMA A0xB1; vmw<W1>; BAR
//   P2: dsA1;      stage A1(t+1);        BAR; lgkm0; MFMA A1xB1;           BAR
//   P3: stage A0(t+2)->CUR buf;               MFMA A1xB0;        vmw<W3>; BAR
// Waits (LA=BM*4/TPB, LB=BN*4/TPB loads/unit/thread): W0=2LA+LB (drains
// B1(t)), W1=LA+2LB (drains A1(t)), W3=2LA+LB (drains A0,B0(t+1)); tails
// LA+LB / LA / 0.  Verified per-unit for (LA,LB) in {(2,2),(2,1),(1,2),(1,1)}.
//
// r10: S-GEMM at TPB=1024 (16 waves, 4Mx4N) — same schedule, 4 waves/SIMD
// instead of 2. r9 counters: Occupancy 20%, MfmaUtil 40%, 53% of cycles
// stalled at barriers with only 2 waves/SIMD to hide them. Wave-grid
// generalization: WM=TPB/256, per-wave M span BM/WM, A-half strip
// QS=BM/(2*WM) (r9 formulas are the WM=2 case). Also: T+V merged into one
// z=2 launch (V rides T's drain tail), prep_w 3->1 launch, softmax
// pair-layout (single h8 store).
//
// ws layout (144 MiB):
//    0 Th | 16 Tl | 32 xh | 48 xl | 64 VT f16 [4][1024][2048] | 80 S f32 (64)
//   overlay on S (dead before S-GEMM writes):
//    80 Wqh | 82 Wql | 84 Wkh | 86 Wkl | 88 WvT | 90 Nh | 92 Nl | 96 Npart(16)
// ============================================================================

typedef _Float16 h8 __attribute__((ext_vector_type(8)));
typedef _Float16 h4 __attribute__((ext_vector_type(4)));
typedef float    f4 __attribute__((ext_vector_type(4)));

#define BAR() __builtin_amdgcn_s_barrier()
#define LGKM0_FENCE()                                      \
  asm volatile("s_waitcnt lgkmcnt(0)" ::: "memory");       \
  __builtin_amdgcn_sched_barrier(0)

template <int N>
__device__ __forceinline__ void vmw() {
  if constexpr (N == 0) asm volatile("s_waitcnt vmcnt(0)" ::: "memory");
  if constexpr (N == 1) asm volatile("s_waitcnt vmcnt(1)" ::: "memory");
  if constexpr (N == 2) asm volatile("s_waitcnt vmcnt(2)" ::: "memory");
  if constexpr (N == 3) asm volatile("s_waitcnt vmcnt(3)" ::: "memory");
  if constexpr (N == 4) asm volatile("s_waitcnt vmcnt(4)" ::: "memory");
  if constexpr (N == 5) asm volatile("s_waitcnt vmcnt(5)" ::: "memory");
  if constexpr (N == 6) asm volatile("s_waitcnt vmcnt(6)" ::: "memory");
}

__device__ __forceinline__ void gl_lds16(const _Float16* g, _Float16* l) {
  __builtin_amdgcn_global_load_lds(
      (const __attribute__((address_space(1))) unsigned int*)g,
      (__attribute__((address_space(3))) unsigned int*)l, 16, 0, 0);
}

// ---------------------------------------------------------------- prep ----
__global__ __launch_bounds__(256) void prep_x_split_copy(
    const float* __restrict__ x, _Float16* __restrict__ xh,
    _Float16* __restrict__ xl, float* __restrict__ out) {
  size_t i = (size_t)blockIdx.x * 256 + threadIdx.x;  // one f4 per thread
  f4 v = ((const f4*)x)[i];
  h4 hi, lo;
#pragma unroll
  for (int j = 0; j < 4; ++j) {
    _Float16 h = (_Float16)v[j];
    hi[j] = h;
    lo[j] = (_Float16)(v[j] - (float)h);
  }
  ((h4*)xh)[i] = hi;
  ((h4*)xl)[i] = lo;
  size_t r = i >> 8, c = i & 255;       // out[:, :1024] = x (fused copy)
  ((f4*)out)[r * 512 + c] = v;
}

// y=0: Wq hi/lo split; y=1: Wk hi/lo split; y=2: Wv transpose -> f16
__global__ __launch_bounds__(256) void prep_w_all(
    const float* __restrict__ Wq, const float* __restrict__ Wk,
    const float* __restrict__ Wv,
    _Float16* __restrict__ Wqh, _Float16* __restrict__ Wql,
    _Float16* __restrict__ Wkh, _Float16* __restrict__ Wkl,
    _Float16* __restrict__ WvT) {
  __shared__ float tl[32][33];
  if (blockIdx.y < 2) {
    const float* W = blockIdx.y ? Wk : Wq;
    _Float16* Wh = blockIdx.y ? Wkh : Wqh;
    _Float16* Wl = blockIdx.y ? Wkl : Wql;
    size_t i = (size_t)blockIdx.x * 256 + threadIdx.x;
    f4 v = ((const f4*)W)[i];
    h4 hi, lo;
#pragma unroll
    for (int j = 0; j < 4; ++j) {
      _Float16 h = (_Float16)v[j];
      hi[j] = h;
      lo[j] = (_Float16)(v[j] - (float)h);
    }
    ((h4*)Wh)[i] = hi;
    ((h4*)Wl)[i] = lo;
  } else {
    const int tc = blockIdx.x & 31;       // e-tile
    const int tr = blockIdx.x >> 5;       // d-tile
    const int r = threadIdx.x >> 3;       // 0..31
    const int c4 = threadIdx.x & 7;       // 0..7 (f4 chunk)
    f4 v = *(const f4*)&Wv[(size_t)(tr * 32 + r) * 1024 + tc * 32 + c4 * 4];
#pragma unroll
    for (int j = 0; j < 4; ++j) tl[r][c4 * 4 + j] = v[j];
    __syncthreads();
    h4 o;
#pragma unroll
    for (int j = 0; j < 4; ++j) o[j] = (_Float16)tl[c4 * 4 + j][r];
    *(h4*)&WvT[(size_t)(tc * 32 + r) * 1024 + tr * 32 + c4 * 4] = o;
  }
}

// Nh/Nl = split(sum of 4 K-partials)
__global__ __launch_bounds__(256) void nsum(const float* __restrict__ Np,
                                            _Float16* __restrict__ Nh,
                                            _Float16* __restrict__ Nl) {
  size_t i = (size_t)blockIdx.x * 256 + threadIdx.x;  // f4 index over 256K
  const size_t M = 1024 * 1024 / 4;
  f4 v = ((const f4*)Np)[i] + ((const f4*)Np)[i + M] +
         ((const f4*)Np)[i + 2 * M] + ((const f4*)Np)[i + 3 * M];
  h4 hi, lo;
#pragma unroll
  for (int j = 0; j < 4; ++j) {
    _Float16 h = (_Float16)v[j];
    hi[j] = h;
    lo[j] = (_Float16)(v[j] - (float)h);
  }
  ((h4*)Nh)[i] = hi;
  ((h4*)Nl)[i] = lo;
}

// ---------------------------------------------------------------- gemm ----
enum { EM_F32 = 0, EM_QK = 1, EM_VT = 2 };

struct G8 {
  const _Float16* Areg[3]; long zA; int lda;     // A region table
  const _Float16* Breg[4][3]; long zB; int ldb;  // B region table per z
  int NT[4];     // K-tiles per z
  int KB[4];     // K-base per z (global k = KB + kt*64; region = k>>10)
  int emode[4];  // epilogue per z
  float* Cf; long zC; int ldc; float scale;      // EM_F32
  _Float16* Ch[4]; _Float16* Cl[4];              // EM_QK (ld = 1024)
  _Float16* Vt;                                  // EM_VT: [b][1024][2048]
};

template <int BM, int BN, int TPB>
__global__ __launch_bounds__(TPB, TPB == 512 ? 2 : 1) void gemmdp(G8 p) {
  constexpr int WM = TPB / 256;        // wave grid: WM(M) x 4(N)
  constexpr int WN = 4;
  constexpr int MFR = BM / (16 * WM);  // m-frags per wave
  constexpr int MPH = MFR / 2;         // m-frags per A-half
  constexpr int NFR = BN / (16 * WN);  // n-frags per wave
  constexpr int NPH = NFR / 2;         // n-frags per B-half
  constexpr int LA = BM * 4 / TPB;     // gl_lds loads/thread per A-unit
  constexpr int LB = BN * 4 / TPB;
  constexpr int RPI = TPB / 8;         // staging rows per issue-iter
  __shared__ alignas(16) _Float16 ldsA[2][BM][64];
  __shared__ alignas(16) _Float16 ldsB[2][BN][64];

  const int t0 = threadIdx.x;
  const int lane = t0 & 63;
  const int w = t0 >> 6;
  const int wm = w >> 2, wn = w & 3;
  const int l15 = lane & 15, l4 = lane >> 4;

  // T1: bijective XCD swizzle (all launches have nwg % 8 == 0)
  const int nbx = gridDim.x, nby = gridDim.y;
  const int nwg = nbx * nby * gridDim.z;
  const int bid = blockIdx.x + nbx * (blockIdx.y + nby * blockIdx.z);
  const int nb = (bid & 7) * (nwg >> 3) + (bid >> 3);
  const int bx = nb % nbx, by = (nb / nbx) % nby, z = nb / (nbx * nby);

  const long Mb = (long)by * BM;
  const long Nb = (long)bx * BN;
  const int nt = p.NT[z];
  const int kb = p.KB[z];
  const long zAo = p.zA * z;
  const long zBo = p.zB * z;
  const int lda = p.lda, ldb = p.ldb;

  const int rr_lo = t0 >> 3;            // staging: 8 lanes per 64-f16 row
  const int slot = t0 & 7;
  const int rr0_lo = (t0 & ~63) >> 3;   // wave-uniform row part

  f4 acc[MFR][NFR] = {};

  // stage unit u (0:A-half0, 1:B-half0, 2:B-half1, 3:A-half1) of kt -> buf sb
  // A-half qm rows: {s*2QS + qm*QS + [0,QS) }, QS = BM/(2*WM)  (= dsA rows)
  // B-half hh rows: {s*2BQ + hh*BQ + [0,BQ) }, BQ = BN/(2*WN)  (= dsB rows)
  auto stageU = [&](int u, int sb, int kt) {
    const int k0 = kb + (kt << 6);
    const int r = k0 >> 10;
    const int cn = k0 & 1023;
    if (u == 0 || u == 3) {
      const _Float16* Ab = p.Areg[r] + zAo + cn;
      const int qm = (u == 3);
      constexpr int QS = BM / (2 * WM);
#pragma unroll
      for (int i = 0; i < LA; ++i) {
        int rr = i * RPI + rr_lo;
        int rr0 = i * RPI + rr0_lo;
        int row  = (rr  / QS) * (2 * QS) + qm * QS + (rr  % QS);
        int row0 = (rr0 / QS) * (2 * QS) + qm * QS + (rr0 % QS);
        int scol = (slot ^ (row & 7)) << 3;     // pre-swizzled source (T2)
        gl_lds16(Ab + (Mb + row) * (long)lda + scol, &ldsA[sb][row0][0]);
      }
    } else {
      const _Float16* Bb = p.Breg[z][r] + zBo + cn;
      const int hh = (u == 2);
      constexpr int BQ = BN / (2 * WN);
#pragma unroll
      for (int i = 0; i < LB; ++i) {
        int rr = i * RPI + rr_lo;
        int rr0 = i * RPI + rr0_lo;
        int row  = (rr  / BQ) * (2 * BQ) + hh * BQ + (rr  % BQ);
        int row0 = (rr0 / BQ) * (2 * BQ) + hh * BQ + (rr0 % BQ);
        int scol = (slot ^ (row & 7)) << 3;
        gl_lds16(Bb + (Nb + row) * (long)ldb + scol, &ldsB[sb][row0][0]);
      }
    }
  };

  h8 af[MPH][2];        // current A-half (reused across 2 phases)
  h8 bfh[2][NPH][2];    // both B-halves (B0 live P0->P3)

  auto dsA = [&](int qm, int buf) {
#pragma unroll
    for (int m = 0; m < MPH; ++m) {
      int row = wm * (BM / WM) + (qm * MPH + m) * 16 + l15;
#pragma unroll
      for (int ks = 0; ks < 2; ++ks)
        af[m][ks] = *(const h8*)&ldsA[buf][row][(((ks * 4 + l4) ^ (row & 7)) << 3)];
    }
  };
  auto dsB = [&](int hh, int buf) {
#pragma unroll
    for (int n = 0; n < NPH; ++n) {
      int row = wn * (BN / WN) + (hh * NPH + n) * 16 + l15;
#pragma unroll
      for (int ks = 0; ks < 2; ++ks)
        bfh[hh][n][ks] = *(const h8*)&ldsB[buf][row][(((ks * 4 + l4) ^ (row & 7)) << 3)];
    }
  };
  auto mfmaQ = [&](int qm, int hh) {
    __builtin_amdgcn_s_setprio(1);
#pragma unroll
    for (int ks = 0; ks < 2; ++ks)
#pragma unroll
      for (int m = 0; m < MPH; ++m)
#pragma unroll
        for (int n = 0; n < NPH; ++n)
          acc[qm * MPH + m][hh * NPH + n] = __builtin_amdgcn_mfma_f32_16x16x32_f16(
              af[m][ks], bfh[hh][n][ks], acc[qm * MPH + m][hh * NPH + n], 0, 0, 0);
    __builtin_amdgcn_s_setprio(0);
  };

  // lazy-publish waits (r9 ledger; verified for LA,LB in {1,2})
  constexpr int W0  = 2 * LA + LB;   // P0-end: drains B1(t)
  constexpr int W1  = LA + 2 * LB;   // P1-end: drains A1(t)
  constexpr int W3  = 2 * LA + LB;   // P3-end: drains A0,B0(t+1)
  constexpr int W3b = LA + LB;       // tail nt-2 P3-end
  constexpr int W0c = LA;            // tail nt-1 P0-end

  // prologue: tile0 (A0,B0,B1,A1) -> buf0; A0(1) -> buf1
  stageU(0, 0, 0); stageU(1, 0, 0); stageU(2, 0, 0); stageU(3, 0, 0);
  stageU(0, 1, 1);
  vmw<W3>();
  BAR();

  int kt = 0;
  for (; kt + 2 < nt; ++kt) {
    const int buf = kt & 1;
    // P0
    dsA(0, buf); dsB(0, buf);
    stageU(1, buf ^ 1, kt + 1);
    BAR(); LGKM0_FENCE();
    mfmaQ(0, 0);
    vmw<W0>(); BAR();
    // P1
    dsB(1, buf);
    stageU(2, buf ^ 1, kt + 1);
    BAR(); LGKM0_FENCE();
    mfmaQ(0, 1);
    vmw<W1>(); BAR();
    // P2
    dsA(1, buf);
    stageU(3, buf ^ 1, kt + 1);
    BAR(); LGKM0_FENCE();
    mfmaQ(1, 1);
    BAR();
    // P3 (regs only; A0(t+2) -> CURRENT buf, region read-dead since P0)
    stageU(0, buf, kt + 2);
    mfmaQ(1, 0);
    vmw<W3>(); BAR();
  }
  {  // kt = nt-2: stages B0,B1,A1(nt-1) only
    const int buf = kt & 1;
    dsA(0, buf); dsB(0, buf);
    stageU(1, buf ^ 1, kt + 1);
    BAR(); LGKM0_FENCE();
    mfmaQ(0, 0);
    vmw<W0>(); BAR();
    dsB(1, buf);
    stageU(2, buf ^ 1, kt + 1);
    BAR(); LGKM0_FENCE();
    mfmaQ(0, 1);
    vmw<W1>(); BAR();
    dsA(1, buf);
    stageU(3, buf ^ 1, kt + 1);
    BAR(); LGKM0_FENCE();
    mfmaQ(1, 1);
    BAR();
    mfmaQ(1, 0);
    vmw<W3b>(); BAR();
    ++kt;
  }
  {  // kt = nt-1: no staging; drain
    const int buf = kt & 1;
    dsA(0, buf); dsB(0, buf);
    BAR(); LGKM0_FENCE();
    mfmaQ(0, 0);
    vmw<W0c>(); BAR();
    dsB(1, buf);
    BAR(); LGKM0_FENCE();
    mfmaQ(0, 1);
    vmw<0>(); BAR();
    dsA(1, buf);
    BAR(); LGKM0_FENCE();
    mfmaQ(1, 1);
    mfmaQ(1, 0);          // epilogue is LDS-free
  }

  // epilogue: C/D map col=lane&15, row=(lane>>4)*4+reg (verified r1..r9)
  const int em = p.emode[z];
  const long gr0 = wm * (BM / WM) + l4 * 4;
  const long gc0 = wn * (BN / WN) + l15;
  if (em == EM_F32) {
    float* C = p.Cf + p.zC * z;
#pragma unroll
    for (int i = 0; i < MFR; ++i)
#pragma unroll
      for (int j = 0; j < NFR; ++j) {
        long gr = Mb + gr0 + i * 16;
        long gc = Nb + gc0 + j * 16;
#pragma unroll
        for (int r = 0; r < 4; ++r)
          C[(gr + r) * (long)p.ldc + gc] = acc[i][j][r] * p.scale;
      }
  } else if (em == EM_QK) {
    _Float16* Ch = p.Ch[z];
    _Float16* Cl = p.Cl[z];
#pragma unroll
    for (int i = 0; i < MFR; ++i)
#pragma unroll
      for (int j = 0; j < NFR; ++j) {
        long gr = Mb + gr0 + i * 16;
        long gc = Nb + gc0 + j * 16;
#pragma unroll
        for (int r = 0; r < 4; ++r) {
          float c = acc[i][j][r];
          _Float16 h = (_Float16)c;
          Ch[(gr + r) * 1024 + gc] = h;
          Cl[(gr + r) * 1024 + gc] = (_Float16)(c - (float)h);
        }
      }
  } else {  // EM_VT: rows = b*2048+s, col = d -> Vt[b][d][s]
    _Float16* Vt = p.Vt;
#pragma unroll
    for (int i = 0; i < MFR; ++i)
#pragma unroll
      for (int j = 0; j < NFR; ++j) {
        long gr = Mb + gr0 + i * 16;
        long gc = Nb + gc0 + j * 16;
        long b = gr >> 11, s = gr & 2047;
        h4 hv;
#pragma unroll
        for (int r = 0; r < 4; ++r) hv[r] = (_Float16)acc[i][j][r];
        *(h4*)&Vt[b * (long)(1024 * 2048) + gc * 2048 + s] = hv;
      }
  }
}

// ------------------------------------------------------------- softmax ----
__global__ __launch_bounds__(256) void softmax_rows(float* __restrict__ Sb) {
  const int t = threadIdx.x;
  float* row = Sb + (size_t)blockIdx.x * 2048;
  f4 v0 = ((const f4*)row)[2 * t];       // cols 8t..8t+3 (32B contiguous)
  f4 v1 = ((const f4*)row)[2 * t + 1];   // cols 8t+4..8t+7
  float mx = -3.0e38f;
#pragma unroll
  for (int j = 0; j < 4; ++j) { mx = fmaxf(mx, v0[j]); mx = fmaxf(mx, v1[j]); }
#pragma unroll
  for (int o = 32; o > 0; o >>= 1) mx = fmaxf(mx, __shfl_xor(mx, o));
  __shared__ float red[4], red2[4];
  const int wave = t >> 6, lane = t & 63;
  if (lane == 0) red[wave] = mx;
  __syncthreads();
  mx = fmaxf(fmaxf(red[0], red[1]), fmaxf(red[2], red[3]));
  float pv[8];
  float sum = 0.f;
#pragma unroll
  for (int j = 0; j < 4; ++j) { pv[j] = __expf(v0[j] - mx); pv[4 + j] = __expf(v1[j] - mx); }
#pragma unroll
  for (int j = 0; j < 8; ++j) sum += pv[j];
#pragma unroll
  for (int o = 32; o > 0; o >>= 1) sum += __shfl_xor(sum, o);
  if (lane == 0) red2[wave] = sum;
  __syncthreads();  // orders all row reads before in-place f16 writes
  sum = red2[0] + red2[1] + red2[2] + red2[3];
  float inv = 1.0f / sum;
  h8 o;
#pragma unroll
  for (int j = 0; j < 4; ++j) { o[j] = (_Float16)(pv[j] * inv); o[4 + j] = (_Float16)(pv[4 + j] * inv); }
  ((h8*)row)[t] = o;   // f16 cols 8t..8t+7, single 16B store
}

// ---------------------------------------------------------------- misc ----
__global__ __launch_bounds__(256) void copy_x_half(const float* __restrict__ x,
                                                   float* __restrict__ out) {
  size_t i = (size_t)blockIdx.x * 256 + threadIdx.x;
  size_t r = i >> 8, c = i & 255;
  ((f4*)out)[r * 512 + c] = ((const f4*)x)[i];
}

__global__ void ws_sentinel(float* out, float v) { out[0] = v; }

// -------------------------------------------------------------- launch ----
extern "C" void kernel_launch(void* const* d_in, const int* in_sizes, int n_in,
                              void* d_out, int out_size, void* d_ws, size_t ws_size,
                              hipStream_t stream) {
  const float* x  = (const float*)d_in[0];
  const float* Wq = (const float*)d_in[1];
  const float* Wk = (const float*)d_in[2];
  const float* Wv = (const float*)d_in[3];
  float* out = (float*)d_out;

  const size_t MB = 1ull << 20;
  char* w = (char*)d_ws;
  _Float16* Th = (_Float16*)(w + 0 * MB);
  _Float16* Tl = (_Float16*)(w + 16 * MB);
  _Float16* xh = (_Float16*)(w + 32 * MB);
  _Float16* xl = (_Float16*)(w + 48 * MB);
  _Float16* VT = (_Float16*)(w + 64 * MB);
  float*    S  = (float*)   (w + 80 * MB);
  // overlay on S (all dead before S-GEMM writes):
  _Float16* Wqh = (_Float16*)(w + 80 * MB);
  _Float16* Wql = (_Float16*)(w + 82 * MB);
  _Float16* Wkh = (_Float16*)(w + 84 * MB);
  _Float16* Wkl = (_Float16*)(w + 86 * MB);
  _Float16* WvT = (_Float16*)(w + 88 * MB);
  _Float16* Nh  = (_Float16*)(w + 90 * MB);
  _Float16* Nl  = (_Float16*)(w + 92 * MB);
  float*    Npart = (float*)(w + 96 * MB);   // 4 x 4 MB f32

  if (ws_size < 144 * MB) {  // fail loud: absmax reports ~ws_size
    copy_x_half<<<8192, 256, 0, stream>>>(x, out);
    ws_sentinel<<<1, 1, 0, stream>>>(out, (float)ws_size);
    return;
  }

  prep_x_split_copy<<<8192, 256, 0, stream>>>(x, xh, xl, out);
  prep_w_all<<<dim3(1024, 3), 256, 0, stream>>>(Wq, Wk, Wv, Wqh, Wql, Wkh,
                                                Wkl, WvT);

  // --- N = Wk Wq^T (split K=3072, K-split over z), 128x128, 256 blocks ---
  G8 pn = {};
  pn.Areg[0] = Wkh; pn.Areg[1] = Wkl; pn.Areg[2] = Wkh; pn.zA = 0; pn.lda = 1024;
  for (int zz = 0; zz < 4; ++zz) {
    pn.Breg[zz][0] = Wqh; pn.Breg[zz][1] = Wqh; pn.Breg[zz][2] = Wql;
    pn.NT[zz] = 12; pn.KB[zz] = zz * 768; pn.emode[zz] = EM_F32;
  }
  pn.zB = 0; pn.ldb = 1024;
  pn.Cf = Npart; pn.zC = 1024L * 1024; pn.ldc = 1024; pn.scale = 1.f;
  gemmdp<128, 128, 512><<<dim3(8, 8, 4), 512, 0, stream>>>(pn);
  nsum<<<1024, 256, 0, stream>>>(Npart, Nh, Nl);

  // --- T = x N^T (z=0, split K=3072) and V = x Wv (z=1, K=1024) in ONE
  //     512-block launch; V blocks fill T's drain tail ---
  G8 pt = {};
  pt.Areg[0] = xh; pt.Areg[1] = xl; pt.Areg[2] = xh; pt.zA = 0; pt.lda = 1024;
  pt.Breg[0][0] = Nh;  pt.Breg[0][1] = Nh;  pt.Breg[0][2] = Nl;
  pt.Breg[1][0] = WvT; pt.Breg[1][1] = WvT; pt.Breg[1][2] = WvT;
  pt.zB = 0; pt.ldb = 1024;
  pt.NT[0] = 48; pt.NT[1] = 16;
  pt.emode[0] = EM_QK; pt.emode[1] = EM_VT;
  pt.Ch[0] = Th; pt.Cl[0] = Tl;
  pt.Vt = VT;
  gemmdp<128, 256, 512><<<dim3(4, 64, 2), 512, 0, stream>>>(pt);

  // --- S = (T x^T)/32 (split K=3072), 256x256, 16 waves, 256 blocks ---
  G8 ps = {};
  ps.Areg[0] = Th; ps.Areg[1] = Tl; ps.Areg[2] = Th;
  ps.zA = 2048L * 1024; ps.lda = 1024;
  for (int zz = 0; zz < 4; ++zz) {
    ps.Breg[zz][0] = xh; ps.Breg[zz][1] = xh; ps.Breg[zz][2] = xl;
    ps.NT[zz] = 48; ps.emode[zz] = EM_F32;
  }
  ps.zB = 2048L * 1024; ps.ldb = 1024;
  ps.Cf = S; ps.zC = 2048L * 2048; ps.ldc = 2048; ps.scale = 0.03125f;
  gemmdp<256, 256, 1024><<<dim3(8, 8, 4), 1024, 0, stream>>>(ps);

  softmax_rows<<<8192, 256, 0, stream>>>(S);

  // --- attn = P @ V -> out[:, :, 1024:], 256x128, 256 blocks ---
  G8 po = {};
  const _Float16* P = (const _Float16*)S;  // rows stride 4096 f16
  po.Areg[0] = P; po.Areg[1] = P + 1024; po.Areg[2] = P;
  po.zA = 2048L * 4096; po.lda = 4096;
  for (int zz = 0; zz < 4; ++zz) {
    po.Breg[zz][0] = VT; po.Breg[zz][1] = VT + 1024; po.Breg[zz][2] = VT;
    po.NT[zz] = 32; po.emode[zz] = EM_F32;
  }
  po.zB = 1024L * 2048; po.ldb = 2048;
  po.Cf = out + 1024; po.zC = 2048L * 2048; po.ldc = 2048; po.scale = 1.f;
  gemmdp<256, 128, 512><<<dim3(8, 8, 4), 512, 0, stream>>>(po);
}

// Round 11
// 302.468 us; speedup vs baseline: 1.3253x; 1.3253x over previous
//
#include <hip/hip_runtime.h>
#include <stdint.h>

// ============================================================================
// AttentionBlock: out = concat([x, softmax(QK^T/32) @ V], -1)
//   B=4, S=2048, D=1024, fp32 in/out.
//
// ALGEBRA: S = x Wq Wk^T x^T.  N := Wk Wq^T (split-K over z), T := x N^T,
// S := T x^T.  fp32 via f16 hi/lo split folded into K: A''=[Ah|Al|Ah],
// B''=[Bh|Bh|Bl], K=3072, per-K-region tables + per-z K-base.
//
// r11 = EXACT r9 configuration (measured best, 305.8us) + two safe micro-opts
// from r10 (merged prep_w_all, softmax pair-layout). r10's post-mortem:
// 16-wave S spilled (VGPR 64, +25MB scratch writes, 176us) and the T+V
// merged launch made 2 imbalanced dispatch rounds — both reverted.
//
// GEMM template (BM x BN, TPB=512, 8 waves 2Mx4N, BK=64, dbuf LDS,
// gload_lds + T2 pre-swizzled source, T1 XCD swizzle), LAZY-PUBLISH
// schedule (measured best of 5 variants):
//   P0: dsA0+dsB0; stage B0(t+1)->buf^1; BAR; lgkm0; MFMA A0xB0; vmw<W0>; BAR
//   P1: dsB1;      stage B1(t+1);        BAR; lgkm0; MFMA A0xB1; vmw<W1>; BAR
//   P2: dsA1;      stage A1(t+1);        BAR; lgkm0; MFMA A1xB1;           BAR
//   P3: stage A0(t+2)->CUR buf;               MFMA A1xB0;        vmw<W3>; BAR
// Waits (LA=BM/128, LB=BN/128 loads/unit/thread): W0=2LA+LB (drains B1(t)),
// W1=LA+2LB (drains A1(t)), W3=2LA+LB (drains A0,B0(t+1)); tails LA+LB/LA/0.
// Each unit publishes at the LATEST barrier before its read (3-4 phase leads).
//
// ws layout (144 MiB):
//    0 Th | 16 Tl | 32 xh | 48 xl | 64 VT f16 [4][1024][2048] | 80 S f32 (64)
//   overlay on S (dead before S-GEMM writes):
//    80 Wqh | 82 Wql | 84 Wkh | 86 Wkl | 88 WvT | 90 Nh | 92 Nl | 96 Npart(16)
// ============================================================================

typedef _Float16 h8 __attribute__((ext_vector_type(8)));
typedef _Float16 h4 __attribute__((ext_vector_type(4)));
typedef float    f4 __attribute__((ext_vector_type(4)));

#define BAR() __builtin_amdgcn_s_barrier()
#define LGKM0_FENCE()                                      \
  asm volatile("s_waitcnt lgkmcnt(0)" ::: "memory");       \
  __builtin_amdgcn_sched_barrier(0)

template <int N>
__device__ __forceinline__ void vmw() {
  if constexpr (N == 0) asm volatile("s_waitcnt vmcnt(0)" ::: "memory");
  if constexpr (N == 1) asm volatile("s_waitcnt vmcnt(1)" ::: "memory");
  if constexpr (N == 2) asm volatile("s_waitcnt vmcnt(2)" ::: "memory");
  if constexpr (N == 3) asm volatile("s_waitcnt vmcnt(3)" ::: "memory");
  if constexpr (N == 4) asm volatile("s_waitcnt vmcnt(4)" ::: "memory");
  if constexpr (N == 5) asm volatile("s_waitcnt vmcnt(5)" ::: "memory");
  if constexpr (N == 6) asm volatile("s_waitcnt vmcnt(6)" ::: "memory");
}

__device__ __forceinline__ void gl_lds16(const _Float16* g, _Float16* l) {
  __builtin_amdgcn_global_load_lds(
      (const __attribute__((address_space(1))) unsigned int*)g,
      (__attribute__((address_space(3))) unsigned int*)l, 16, 0, 0);
}

// ---------------------------------------------------------------- prep ----
__global__ __launch_bounds__(256) void prep_x_split_copy(
    const float* __restrict__ x, _Float16* __restrict__ xh,
    _Float16* __restrict__ xl, float* __restrict__ out) {
  size_t i = (size_t)blockIdx.x * 256 + threadIdx.x;  // one f4 per thread
  f4 v = ((const f4*)x)[i];
  h4 hi, lo;
#pragma unroll
  for (int j = 0; j < 4; ++j) {
    _Float16 h = (_Float16)v[j];
    hi[j] = h;
    lo[j] = (_Float16)(v[j] - (float)h);
  }
  ((h4*)xh)[i] = hi;
  ((h4*)xl)[i] = lo;
  size_t r = i >> 8, c = i & 255;       // out[:, :1024] = x (fused copy)
  ((f4*)out)[r * 512 + c] = v;
}

// y=0: Wq hi/lo split; y=1: Wk hi/lo split; y=2: Wv transpose -> f16
__global__ __launch_bounds__(256) void prep_w_all(
    const float* __restrict__ Wq, const float* __restrict__ Wk,
    const float* __restrict__ Wv,
    _Float16* __restrict__ Wqh, _Float16* __restrict__ Wql,
    _Float16* __restrict__ Wkh, _Float16* __restrict__ Wkl,
    _Float16* __restrict__ WvT) {
  __shared__ float tl[32][33];
  if (blockIdx.y < 2) {
    const float* W = blockIdx.y ? Wk : Wq;
    _Float16* Wh = blockIdx.y ? Wkh : Wqh;
    _Float16* Wl = blockIdx.y ? Wkl : Wql;
    size_t i = (size_t)blockIdx.x * 256 + threadIdx.x;
    f4 v = ((const f4*)W)[i];
    h4 hi, lo;
#pragma unroll
    for (int j = 0; j < 4; ++j) {
      _Float16 h = (_Float16)v[j];
      hi[j] = h;
      lo[j] = (_Float16)(v[j] - (float)h);
    }
    ((h4*)Wh)[i] = hi;
    ((h4*)Wl)[i] = lo;
  } else {
    const int tc = blockIdx.x & 31;       // e-tile
    const int tr = blockIdx.x >> 5;       // d-tile
    const int r = threadIdx.x >> 3;       // 0..31
    const int c4 = threadIdx.x & 7;       // 0..7 (f4 chunk)
    f4 v = *(const f4*)&Wv[(size_t)(tr * 32 + r) * 1024 + tc * 32 + c4 * 4];
#pragma unroll
    for (int j = 0; j < 4; ++j) tl[r][c4 * 4 + j] = v[j];
    __syncthreads();
    h4 o;
#pragma unroll
    for (int j = 0; j < 4; ++j) o[j] = (_Float16)tl[c4 * 4 + j][r];
    *(h4*)&WvT[(size_t)(tc * 32 + r) * 1024 + tr * 32 + c4 * 4] = o;
  }
}

// Nh/Nl = split(sum of 4 K-partials)
__global__ __launch_bounds__(256) void nsum(const float* __restrict__ Np,
                                            _Float16* __restrict__ Nh,
                                            _Float16* __restrict__ Nl) {
  size_t i = (size_t)blockIdx.x * 256 + threadIdx.x;  // f4 index over 256K
  const size_t M = 1024 * 1024 / 4;
  f4 v = ((const f4*)Np)[i] + ((const f4*)Np)[i + M] +
         ((const f4*)Np)[i + 2 * M] + ((const f4*)Np)[i + 3 * M];
  h4 hi, lo;
#pragma unroll
  for (int j = 0; j < 4; ++j) {
    _Float16 h = (_Float16)v[j];
    hi[j] = h;
    lo[j] = (_Float16)(v[j] - (float)h);
  }
  ((h4*)Nh)[i] = hi;
  ((h4*)Nl)[i] = lo;
}

// ---------------------------------------------------------------- gemm ----
enum { EM_F32 = 0, EM_QK = 1, EM_VT = 2 };

struct G8 {
  const _Float16* Areg[3]; long zA; int lda;     // A region table
  const _Float16* Breg[4][3]; long zB; int ldb;  // B region table per z
  int NT[4];     // K-tiles per z
  int KB[4];     // K-base per z (global k = KB + kt*64; region = k>>10)
  int emode[4];  // epilogue per z
  float* Cf; long zC; int ldc; float scale;      // EM_F32
  _Float16* Ch[4]; _Float16* Cl[4];              // EM_QK (ld = 1024)
  _Float16* Vt;                                  // EM_VT: [b][1024][2048]
};

template <int BM, int BN>
__global__ __launch_bounds__(512, 2) void gemmdp(G8 p) {
  constexpr int MFR = BM / 32;
  constexpr int MPH = MFR / 2;
  constexpr int NFR = BN / 64;
  constexpr int NPH = NFR / 2;
  constexpr int LA = BM / 128;   // loads/thread per A-unit
  constexpr int LB = BN / 128;
  __shared__ alignas(16) _Float16 ldsA[2][BM][64];
  __shared__ alignas(16) _Float16 ldsB[2][BN][64];

  const int t0 = threadIdx.x;
  const int lane = t0 & 63;
  const int w = t0 >> 6;
  const int wm = w >> 2, wn = w & 3;           // wave grid 2(M) x 4(N)
  const int l15 = lane & 15, l4 = lane >> 4;

  // T1: bijective XCD swizzle (all launches have nwg % 8 == 0)
  const int nbx = gridDim.x, nby = gridDim.y;
  const int nwg = nbx * nby * gridDim.z;
  const int bid = blockIdx.x + nbx * (blockIdx.y + nby * blockIdx.z);
  const int nb = (bid & 7) * (nwg >> 3) + (bid >> 3);
  const int bx = nb % nbx, by = (nb / nbx) % nby, z = nb / (nbx * nby);

  const long Mb = (long)by * BM;
  const long Nb = (long)bx * BN;
  const int nt = p.NT[z];
  const int kb = p.KB[z];
  const long zAo = p.zA * z;
  const long zBo = p.zB * z;
  const int lda = p.lda, ldb = p.ldb;

  const int rr_lo = t0 >> 3;            // staging: 8 lanes per 64-f16 row
  const int slot = t0 & 7;
  const int rr0_lo = (t0 & ~63) >> 3;   // wave-uniform row part

  f4 acc[MFR][NFR] = {};

  // stage unit u (0:A-half0, 1:B-half0, 2:B-half1, 3:A-half1) of kt -> buf sb
  // A-half qm rows: {s*(BM/2) + qm*(BM/4) + [0,BM/4) : s<2}   (= dsA rows)
  // B-half hh rows: {s*(BN/4) + hh*(BN/8) + [0,BN/8) : s<4}   (= dsB rows)
  auto stageU = [&](int u, int sb, int kt) {
    const int k0 = kb + (kt << 6);
    const int r = k0 >> 10;
    const int cn = k0 & 1023;
    if (u == 0 || u == 3) {
      const _Float16* Ab = p.Areg[r] + zAo + cn;
      const int qm = (u == 3);
      constexpr int QS = BM / 4;
#pragma unroll
      for (int i = 0; i < LA; ++i) {
        int rr = i * 64 + rr_lo;
        int rr0 = i * 64 + rr0_lo;
        int row  = (rr  / QS) * (BM / 2) + qm * QS + (rr  % QS);
        int row0 = (rr0 / QS) * (BM / 2) + qm * QS + (rr0 % QS);
        int scol = (slot ^ (row & 7)) << 3;     // pre-swizzled source (T2)
        gl_lds16(Ab + (Mb + row) * (long)lda + scol, &ldsA[sb][row0][0]);
      }
    } else {
      const _Float16* Bb = p.Breg[z][r] + zBo + cn;
      const int hh = (u == 2);
      constexpr int BQ = BN / 8;
#pragma unroll
      for (int i = 0; i < LB; ++i) {
        int rr = i * 64 + rr_lo;
        int rr0 = i * 64 + rr0_lo;
        int row  = (rr  / BQ) * (BN / 4) + hh * BQ + (rr  % BQ);
        int row0 = (rr0 / BQ) * (BN / 4) + hh * BQ + (rr0 % BQ);
        int scol = (slot ^ (row & 7)) << 3;
        gl_lds16(Bb + (Nb + row) * (long)ldb + scol, &ldsB[sb][row0][0]);
      }
    }
  };

  h8 af[MPH][2];        // current A-half (reused across 2 phases)
  h8 bfh[2][NPH][2];    // both B-halves (B0 live P0->P3)

  auto dsA = [&](int qm, int buf) {
#pragma unroll
    for (int m = 0; m < MPH; ++m) {
      int row = wm * (BM / 2) + (qm * MPH + m) * 16 + l15;
#pragma unroll
      for (int ks = 0; ks < 2; ++ks)
        af[m][ks] = *(const h8*)&ldsA[buf][row][(((ks * 4 + l4) ^ (row & 7)) << 3)];
    }
  };
  auto dsB = [&](int hh, int buf) {
#pragma unroll
    for (int n = 0; n < NPH; ++n) {
      int row = wn * (16 * NFR) + (hh * NPH + n) * 16 + l15;
#pragma unroll
      for (int ks = 0; ks < 2; ++ks)
        bfh[hh][n][ks] = *(const h8*)&ldsB[buf][row][(((ks * 4 + l4) ^ (row & 7)) << 3)];
    }
  };
  auto mfmaQ = [&](int qm, int hh) {
    __builtin_amdgcn_s_setprio(1);
#pragma unroll
    for (int ks = 0; ks < 2; ++ks)
#pragma unroll
      for (int m = 0; m < MPH; ++m)
#pragma unroll
        for (int n = 0; n < NPH; ++n)
          acc[qm * MPH + m][hh * NPH + n] = __builtin_amdgcn_mfma_f32_16x16x32_f16(
              af[m][ks], bfh[hh][n][ks], acc[qm * MPH + m][hh * NPH + n], 0, 0, 0);
    __builtin_amdgcn_s_setprio(0);
  };

  // lazy-publish waits (r9 ledger)
  constexpr int W0  = 2 * LA + LB;   // P0-end: drains B1(t)
  constexpr int W1  = LA + 2 * LB;   // P1-end: drains A1(t)
  constexpr int W3  = 2 * LA + LB;   // P3-end: drains A0,B0(t+1)
  constexpr int W3b = LA + LB;       // tail nt-2 P3-end
  constexpr int W0c = LA;            // tail nt-1 P0-end

  // prologue: tile0 (A0,B0,B1,A1) -> buf0; A0(1) -> buf1
  stageU(0, 0, 0); stageU(1, 0, 0); stageU(2, 0, 0); stageU(3, 0, 0);
  stageU(0, 1, 1);
  vmw<W3>();
  BAR();

  int kt = 0;
  for (; kt + 2 < nt; ++kt) {
    const int buf = kt & 1;
    // P0
    dsA(0, buf); dsB(0, buf);
    stageU(1, buf ^ 1, kt + 1);
    BAR(); LGKM0_FENCE();
    mfmaQ(0, 0);
    vmw<W0>(); BAR();
    // P1
    dsB(1, buf);
    stageU(2, buf ^ 1, kt + 1);
    BAR(); LGKM0_FENCE();
    mfmaQ(0, 1);
    vmw<W1>(); BAR();
    // P2
    dsA(1, buf);
    stageU(3, buf ^ 1, kt + 1);
    BAR(); LGKM0_FENCE();
    mfmaQ(1, 1);
    BAR();
    // P3 (regs only; A0(t+2) -> CURRENT buf, region read-dead since P0)
    stageU(0, buf, kt + 2);
    mfmaQ(1, 0);
    vmw<W3>(); BAR();
  }
  {  // kt = nt-2: stages B0,B1,A1(nt-1) only
    const int buf = kt & 1;
    dsA(0, buf); dsB(0, buf);
    stageU(1, buf ^ 1, kt + 1);
    BAR(); LGKM0_FENCE();
    mfmaQ(0, 0);
    vmw<W0>(); BAR();
    dsB(1, buf);
    stageU(2, buf ^ 1, kt + 1);
    BAR(); LGKM0_FENCE();
    mfmaQ(0, 1);
    vmw<W1>(); BAR();
    dsA(1, buf);
    stageU(3, buf ^ 1, kt + 1);
    BAR(); LGKM0_FENCE();
    mfmaQ(1, 1);
    BAR();
    mfmaQ(1, 0);
    vmw<W3b>(); BAR();
    ++kt;
  }
  {  // kt = nt-1: no staging; drain
    const int buf = kt & 1;
    dsA(0, buf); dsB(0, buf);
    BAR(); LGKM0_FENCE();
    mfmaQ(0, 0);
    vmw<W0c>(); BAR();
    dsB(1, buf);
    BAR(); LGKM0_FENCE();
    mfmaQ(0, 1);
    vmw<0>(); BAR();
    dsA(1, buf);
    BAR(); LGKM0_FENCE();
    mfmaQ(1, 1);
    mfmaQ(1, 0);          // epilogue is LDS-free
  }

  // epilogue: C/D map col=lane&15, row=(lane>>4)*4+reg (verified r1..r10)
  const int em = p.emode[z];
  const long gr0 = wm * (BM / 2) + l4 * 4;
  const long gc0 = wn * (16 * NFR) + l15;
  if (em == EM_F32) {
    float* C = p.Cf + p.zC * z;
#pragma unroll
    for (int i = 0; i < MFR; ++i)
#pragma unroll
      for (int j = 0; j < NFR; ++j) {
        long gr = Mb + gr0 + i * 16;
        long gc = Nb + gc0 + j * 16;
#pragma unroll
        for (int r = 0; r < 4; ++r)
          C[(gr + r) * (long)p.ldc + gc] = acc[i][j][r] * p.scale;
      }
  } else if (em == EM_QK) {
    _Float16* Ch = p.Ch[z];
    _Float16* Cl = p.Cl[z];
#pragma unroll
    for (int i = 0; i < MFR; ++i)
#pragma unroll
      for (int j = 0; j < NFR; ++j) {
        long gr = Mb + gr0 + i * 16;
        long gc = Nb + gc0 + j * 16;
#pragma unroll
        for (int r = 0; r < 4; ++r) {
          float c = acc[i][j][r];
          _Float16 h = (_Float16)c;
          Ch[(gr + r) * 1024 + gc] = h;
          Cl[(gr + r) * 1024 + gc] = (_Float16)(c - (float)h);
        }
      }
  } else {  // EM_VT: rows = b*2048+s, col = d -> Vt[b][d][s]
    _Float16* Vt = p.Vt;
#pragma unroll
    for (int i = 0; i < MFR; ++i)
#pragma unroll
      for (int j = 0; j < NFR; ++j) {
        long gr = Mb + gr0 + i * 16;
        long gc = Nb + gc0 + j * 16;
        long b = gr >> 11, s = gr & 2047;
        h4 hv;
#pragma unroll
        for (int r = 0; r < 4; ++r) hv[r] = (_Float16)acc[i][j][r];
        *(h4*)&Vt[b * (long)(1024 * 2048) + gc * 2048 + s] = hv;
      }
  }
}

// ------------------------------------------------------------- softmax ----
__global__ __launch_bounds__(256) void softmax_rows(float* __restrict__ Sb) {
  const int t = threadIdx.x;
  float* row = Sb + (size_t)blockIdx.x * 2048;
  f4 v0 = ((const f4*)row)[2 * t];       // cols 8t..8t+3
  f4 v1 = ((const f4*)row)[2 * t + 1];   // cols 8t+4..8t+7
  float mx = -3.0e38f;
#pragma unroll
  for (int j = 0; j < 4; ++j) { mx = fmaxf(mx, v0[j]); mx = fmaxf(mx, v1[j]); }
#pragma unroll
  for (int o = 32; o > 0; o >>= 1) mx = fmaxf(mx, __shfl_xor(mx, o));
  __shared__ float red[4], red2[4];
  const int wave = t >> 6, lane = t & 63;
  if (lane == 0) red[wave] = mx;
  __syncthreads();
  mx = fmaxf(fmaxf(red[0], red[1]), fmaxf(red[2], red[3]));
  float pv[8];
  float sum = 0.f;
#pragma unroll
  for (int j = 0; j < 4; ++j) { pv[j] = __expf(v0[j] - mx); pv[4 + j] = __expf(v1[j] - mx); }
#pragma unroll
  for (int j = 0; j < 8; ++j) sum += pv[j];
#pragma unroll
  for (int o = 32; o > 0; o >>= 1) sum += __shfl_xor(sum, o);
  if (lane == 0) red2[wave] = sum;
  __syncthreads();  // orders all row reads before in-place f16 writes
  sum = red2[0] + red2[1] + red2[2] + red2[3];
  float inv = 1.0f / sum;
  h8 o;
#pragma unroll
  for (int j = 0; j < 4; ++j) { o[j] = (_Float16)(pv[j] * inv); o[4 + j] = (_Float16)(pv[4 + j] * inv); }
  ((h8*)row)[t] = o;   // f16 cols 8t..8t+7, single 16B store
}

// ---------------------------------------------------------------- misc ----
__global__ __launch_bounds__(256) void copy_x_half(const float* __restrict__ x,
                                                   float* __restrict__ out) {
  size_t i = (size_t)blockIdx.x * 256 + threadIdx.x;
  size_t r = i >> 8, c = i & 255;
  ((f4*)out)[r * 512 + c] = ((const f4*)x)[i];
}

__global__ void ws_sentinel(float* out, float v) { out[0] = v; }

// -------------------------------------------------------------- launch ----
extern "C" void kernel_launch(void* const* d_in, const int* in_sizes, int n_in,
                              void* d_out, int out_size, void* d_ws, size_t ws_size,
                              hipStream_t stream) {
  const float* x  = (const float*)d_in[0];
  const float* Wq = (const float*)d_in[1];
  const float* Wk = (const float*)d_in[2];
  const float* Wv = (const float*)d_in[3];
  float* out = (float*)d_out;

  const size_t MB = 1ull << 20;
  char* w = (char*)d_ws;
  _Float16* Th = (_Float16*)(w + 0 * MB);
  _Float16* Tl = (_Float16*)(w + 16 * MB);
  _Float16* xh = (_Float16*)(w + 32 * MB);
  _Float16* xl = (_Float16*)(w + 48 * MB);
  _Float16* VT = (_Float16*)(w + 64 * MB);
  float*    S  = (float*)   (w + 80 * MB);
  // overlay on S (all dead before S-GEMM writes):
  _Float16* Wqh = (_Float16*)(w + 80 * MB);
  _Float16* Wql = (_Float16*)(w + 82 * MB);
  _Float16* Wkh = (_Float16*)(w + 84 * MB);
  _Float16* Wkl = (_Float16*)(w + 86 * MB);
  _Float16* WvT = (_Float16*)(w + 88 * MB);
  _Float16* Nh  = (_Float16*)(w + 90 * MB);
  _Float16* Nl  = (_Float16*)(w + 92 * MB);
  float*    Npart = (float*)(w + 96 * MB);   // 4 x 4 MB f32

  if (ws_size < 144 * MB) {  // fail loud: absmax reports ~ws_size
    copy_x_half<<<8192, 256, 0, stream>>>(x, out);
    ws_sentinel<<<1, 1, 0, stream>>>(out, (float)ws_size);
    return;
  }

  prep_x_split_copy<<<8192, 256, 0, stream>>>(x, xh, xl, out);
  prep_w_all<<<dim3(1024, 3), 256, 0, stream>>>(Wq, Wk, Wv, Wqh, Wql, Wkh,
                                                Wkl, WvT);

  // --- N = Wk Wq^T (split K=3072, K-split over z), 128x128, 256 blocks ---
  G8 pn = {};
  pn.Areg[0] = Wkh; pn.Areg[1] = Wkl; pn.Areg[2] = Wkh; pn.zA = 0; pn.lda = 1024;
  for (int zz = 0; zz < 4; ++zz) {
    pn.Breg[zz][0] = Wqh; pn.Breg[zz][1] = Wqh; pn.Breg[zz][2] = Wql;
    pn.NT[zz] = 12; pn.KB[zz] = zz * 768; pn.emode[zz] = EM_F32;
  }
  pn.zB = 0; pn.ldb = 1024;
  pn.Cf = Npart; pn.zC = 1024L * 1024; pn.ldc = 1024; pn.scale = 1.f;
  gemmdp<128, 128><<<dim3(8, 8, 4), 512, 0, stream>>>(pn);
  nsum<<<1024, 256, 0, stream>>>(Npart, Nh, Nl);

  // --- T = x @ N^T-layout (split K=3072), 128x256 -> 256 blocks ---
  G8 pt = {};
  pt.Areg[0] = xh; pt.Areg[1] = xl; pt.Areg[2] = xh; pt.zA = 0; pt.lda = 1024;
  pt.Breg[0][0] = Nh; pt.Breg[0][1] = Nh; pt.Breg[0][2] = Nl;
  pt.zB = 0; pt.ldb = 1024;
  pt.NT[0] = 48; pt.emode[0] = EM_QK;
  pt.Ch[0] = Th; pt.Cl[0] = Tl;
  gemmdp<128, 256><<<dim3(4, 64, 1), 512, 0, stream>>>(pt);

  // --- V = x @ Wv (plain, K=1024), 128x256 -> 256 blocks, stored VT ---
  G8 pv = {};
  pv.Areg[0] = xh; pv.Areg[1] = xh; pv.Areg[2] = xh; pv.zA = 0; pv.lda = 1024;
  pv.Breg[0][0] = WvT; pv.Breg[0][1] = WvT; pv.Breg[0][2] = WvT;
  pv.zB = 0; pv.ldb = 1024;
  pv.NT[0] = 16; pv.emode[0] = EM_VT;
  pv.Vt = VT;
  gemmdp<128, 256><<<dim3(4, 64, 1), 512, 0, stream>>>(pv);

  // --- S = (T x^T)/32 (split K=3072), 256x256, 256 blocks ---
  G8 ps = {};
  ps.Areg[0] = Th; ps.Areg[1] = Tl; ps.Areg[2] = Th;
  ps.zA = 2048L * 1024; ps.lda = 1024;
  for (int zz = 0; zz < 4; ++zz) {
    ps.Breg[zz][0] = xh; ps.Breg[zz][1] = xh; ps.Breg[zz][2] = xl;
    ps.NT[zz] = 48; ps.emode[zz] = EM_F32;
  }
  ps.zB = 2048L * 1024; ps.ldb = 1024;
  ps.Cf = S; ps.zC = 2048L * 2048; ps.ldc = 2048; ps.scale = 0.03125f;
  gemmdp<256, 256><<<dim3(8, 8, 4), 512, 0, stream>>>(ps);

  softmax_rows<<<8192, 256, 0, stream>>>(S);

  // --- attn = P @ V -> out[:, :, 1024:], 256x128, 256 blocks ---
  G8 po = {};
  const _Float16* P = (const _Float16*)S;  // rows stride 4096 f16
  po.Areg[0] = P; po.Areg[1] = P + 1024; po.Areg[2] = P;
  po.zA = 2048L * 4096; po.lda = 4096;
  for (int zz = 0; zz < 4; ++zz) {
    po.Breg[zz][0] = VT; po.Breg[zz][1] = VT + 1024; po.Breg[zz][2] = VT;
    po.NT[zz] = 32; po.emode[zz] = EM_F32;
  }
  po.zB = 1024L * 2048; po.ldb = 2048;
  po.Cf = out + 1024; po.zC = 2048L * 2048; po.ldc = 2048; po.scale = 1.f;
  gemmdp<256, 128><<<dim3(8, 8, 4), 512, 0, stream>>>(po);
}